// Round 1
// baseline (504.300 us; speedup 1.0000x reference)
//
#include <hip/hip_runtime.h>

// SparseLinear: out[32,65536] = x[32,1024] @ (w * mask)[1024,65536] + b, fp32.
// Memory-bound floor: stream w+mask once = 512 MB -> ~82 us @ 6.3 TB/s.
//
// R1 post-mortem: 1 block/CU (11.5% occupancy) + per-kl load/use interleave
// -> latency-bound at 8% HBM. Fix: KSPLIT=4 over gridDim.y (16 waves/CU) +
// explicit depth-1 software pipeline with U=8 load groups (16 loads in
// flight per wave), barrier-free main loop.
//
// R2 (this round): rocprof showed 2x 1-GiB fillBuffer dispatches per timed
// iteration (~322 us) = harness re-poisoning the WORKSPACE. sl_partial itself
// is <161 us (absent from top-5). Fix: drop the workspace path entirely.
// sl_init writes out = b (8 MB, ~2 us), then sl_partial<true> atomicAdd's
// partials directly into out (8.4M coalesced f32 atomics, ~33 MB L2 RMW,
// 4-way same-address contention). Also deletes the 128 MB partial write and
// the 136 MB sl_reduce pass (~22 us).

#define IN_DIM 1024
#define OUT_DIM 65536
#define BATCH 32
#define KSPLIT 4
#define KCHUNK (IN_DIM / KSPLIT)   // 256
#define BLOCK 256
#define U 8
#define NG (KCHUNK / U)            // 32 groups per block

__global__ __launch_bounds__(BLOCK, 4) void sl_partial(
    const float* __restrict__ x, const float* __restrict__ mask,
    const float* __restrict__ w, float* __restrict__ dst) {
  __shared__ float xT[KCHUNK * BATCH];  // 32 KB: xT[kl*32+i] = x[i][k0+kl]
  const int tid = threadIdx.x;
  const int j = blockIdx.x * BLOCK + tid;
  const int kc = blockIdx.y;
  const int k0 = kc * KCHUNK;

  // One-time stage of this block's x chunk (coalesced global reads; the
  // 64-way LDS write conflict here is one-time, ~2K cyc/block, <2%).
#pragma unroll
  for (int it = 0; it < (KCHUNK * BATCH) / BLOCK; ++it) {
    int idx = it * BLOCK + tid;
    int kl = idx & (KCHUNK - 1);
    int i = idx >> 8;  // KCHUNK == 256
    xT[kl * BATCH + i] = x[i * IN_DIM + k0 + kl];
  }
  __syncthreads();  // only barrier in the kernel

  float acc[BATCH];
#pragma unroll
  for (int i = 0; i < BATCH; ++i) acc[i] = 0.0f;

  const float* wp = w + (size_t)k0 * OUT_DIM + j;
  const float* mp = mask + (size_t)k0 * OUT_DIM + j;

  float wA[U], mA[U], wB[U], mB[U];

  auto loadg = [&](int g, float* wv, float* mv) {
#pragma unroll
    for (int u = 0; u < U; ++u) {
      size_t off = (size_t)(g * U + u) * OUT_DIM;
      wv[u] = __builtin_nontemporal_load(wp + off);  // streaming, no reuse
      mv[u] = __builtin_nontemporal_load(mp + off);
    }
  };
  auto computeg = [&](int g, const float* wv, const float* mv) {
#pragma unroll
    for (int u = 0; u < U; ++u) {
      float wm = wv[u] * mv[u];
      const float4* xp = (const float4*)&xT[(g * U + u) * BATCH];
#pragma unroll
      for (int i4 = 0; i4 < BATCH / 4; ++i4) {
        float4 q = xp[i4];  // wave-uniform address -> LDS broadcast
        acc[i4 * 4 + 0] = fmaf(q.x, wm, acc[i4 * 4 + 0]);
        acc[i4 * 4 + 1] = fmaf(q.y, wm, acc[i4 * 4 + 1]);
        acc[i4 * 4 + 2] = fmaf(q.z, wm, acc[i4 * 4 + 2]);
        acc[i4 * 4 + 3] = fmaf(q.w, wm, acc[i4 * 4 + 3]);
      }
    }
  };

  // Depth-1 software pipeline: loads for phase g+1 are issued before the
  // compute of phase g completes -> 16 dword loads (4 KB/wave) in flight.
  loadg(0, wA, mA);
#pragma unroll 1
  for (int g = 0; g < NG; g += 2) {
    loadg(g + 1, wB, mB);  // g+1 <= NG-1 always (NG even)
    computeg(g, wA, mA);
    if (g + 2 < NG) loadg(g + 2, wA, mA);
    computeg(g + 1, wB, mB);
  }

  // Accumulate directly into out (pre-initialized to b by sl_init).
  // 32 atomics/thread, 64 lanes contiguous (256 B/instr) -> coalesced L2 RMW.
#pragma unroll
  for (int i = 0; i < BATCH; ++i)
    atomicAdd(dst + (size_t)i * OUT_DIM + j, acc[i]);
}

// out[i][j] = b[j]  (atomic accumulation base; out is re-poisoned per iter)
__global__ __launch_bounds__(BLOCK) void sl_init(
    const float* __restrict__ b, float* __restrict__ out) {
  const int j4 = blockIdx.x * BLOCK + threadIdx.x;
  const float4 bv = ((const float4*)b)[j4];
#pragma unroll
  for (int i = 0; i < BATCH; ++i)
    ((float4*)out)[(size_t)i * (OUT_DIM / 4) + j4] = bv;
}

extern "C" void kernel_launch(void* const* d_in, const int* in_sizes, int n_in,
                              void* d_out, int out_size, void* d_ws, size_t ws_size,
                              hipStream_t stream) {
  const float* x = (const float*)d_in[0];
  const float* mask = (const float*)d_in[1];
  const float* w = (const float*)d_in[2];
  const float* b = (const float*)d_in[3];
  float* out = (float*)d_out;

  // No workspace use: avoids the harness's per-iteration 2x 1-GiB ws
  // re-poison fills (~322 us) that dominated the previous measurement.
  (void)d_ws;
  (void)ws_size;

  hipLaunchKernelGGL(sl_init, dim3(OUT_DIM / 4 / BLOCK), dim3(BLOCK), 0,
                     stream, b, out);
  hipLaunchKernelGGL(sl_partial, dim3(OUT_DIM / BLOCK, KSPLIT), dim3(BLOCK),
                     0, stream, x, mask, w, out);
}